// Round 5
// baseline (1009.050 us; speedup 1.0000x reference)
//
#include <hip/hip_runtime.h>
#include <hip/hip_bf16.h>
#include <stdint.h>

// ClusterAssignment: out[n,k] = q/(row-sum q), q = 1/(1+||x_n-c_k||^2), ALPHA=1
// N=65536, K=1024, D=512, fp32 in/out.
// R5: barrier-free K-loop. R2-R4 (1 block/CU, barrier-coupled staging) all
// stuck at 162-213us: lockstep waves at 2/SIMD can't hide L2 latency and
// every schedule variant exposed it. Now: A panel (128x512, 128KB) staged to
// LDS ONCE (one barrier), B read global->reg per-wave (zero reuse -> no LDS),
// then 16 K-tiles with NO barriers -- compiler hoists B loads freely, waves
// free-run. BM=128 halves B L2 re-reads vs R2/R4. Fused normalize kept.

#define N_ROWS 65536
#define K_CL   1024
#define D_DIM  512
#define BM     128

typedef __attribute__((ext_vector_type(8))) short short8;
typedef __attribute__((ext_vector_type(4))) float f32x4;

__device__ __forceinline__ ushort f2bf(float f) {
    union { float f; uint32_t u; } v; v.f = f;
    uint32_t u = v.u;
    u += 0x7fffu + ((u >> 16) & 1u);   // RNE (inputs are finite normals)
    return (ushort)(u >> 16);
}

__device__ __forceinline__ float waveReduceSum(float s) {
#pragma unroll
    for (int off = 32; off; off >>= 1) s += __shfl_down(s, off, 64);
    return s;
}

// ---- prep: fp32 -> bf16 + row sum-of-squares (one wave per row of 512) ----
__global__ void prep_rows(const float* __restrict__ X, ushort* __restrict__ Xbf,
                          float* __restrict__ sq) {
    const int row  = blockIdx.x * 4 + (threadIdx.x >> 6);
    const int lane = threadIdx.x & 63;
    const float4* src = (const float4*)(X + (size_t)row * D_DIM);
    float4 a = src[lane * 2];
    float4 b = src[lane * 2 + 1];
    float s = (a.x*a.x + a.y*a.y) + (a.z*a.z + a.w*a.w)
            + (b.x*b.x + b.y*b.y) + (b.z*b.z + b.w*b.w);
    uint4 o;
    o.x = (uint32_t)f2bf(a.x) | ((uint32_t)f2bf(a.y) << 16);
    o.y = (uint32_t)f2bf(a.z) | ((uint32_t)f2bf(a.w) << 16);
    o.z = (uint32_t)f2bf(b.x) | ((uint32_t)f2bf(b.y) << 16);
    o.w = (uint32_t)f2bf(b.z) | ((uint32_t)f2bf(b.w) << 16);
    *(uint4*)(Xbf + (size_t)row * D_DIM + lane * 8) = o;
    s = waveReduceSum(s);
    if (lane == 0) sq[row] = s;
}

// ---- fused GEMM + numerator + row-normalize, barrier-free K-loop ----
// Block: 128 rows x full K=1024, 1024 threads = 16 waves as [wr 0..1][wc 0..7];
// wave tile = 64 rows x 128 cols, acc[4][8].
// A in LDS (full panel, staged once, slot-XOR swizzle); B global->reg.
__global__ __launch_bounds__(1024, 2) void gemm_fused(
    const ushort* __restrict__ A, const ushort* __restrict__ B,
    const float* __restrict__ xsq, const float* __restrict__ csq,
    float* __restrict__ out)
{
    // [row][512] bf16 = 1024 B rows, 64 slots of 16 B; LDS slot s of row r
    // holds global slot s ^ (r & 15).
    __shared__ __align__(16) ushort smA[BM * D_DIM];   // 128 KB

    const int tid  = threadIdx.x;
    const int w    = tid >> 6;                 // 0..15
    const int lane = tid & 63;
    const int l4 = lane >> 4, l16 = lane & 15;
    const int wr = w >> 3, wc = w & 7;         // wave tile origin (wr*64, wc*128)
    const int rbase = blockIdx.x * BM;

    // ---- stage full A panel once (8 issues; dest rows are wave-uniform) ----
#pragma unroll
    for (int i = 0; i < 8; ++i) {
        const int row = i * 16 + w;                 // wave-uniform
        const int sl  = lane ^ (row & 15);          // pre-swizzled source slot
        __builtin_amdgcn_global_load_lds(
            (const __attribute__((address_space(1))) void*)
                (A + (size_t)(rbase + row) * D_DIM + sl * 8),
            (__attribute__((address_space(3))) void*)(smA + (size_t)row * D_DIM),
            16, 0, 0);
    }

    // B per-lane fragment bases: row (wc*128 + n*16 + l16), k-slice l4*8
    const ushort* gB[8];
#pragma unroll
    for (int n = 0; n < 8; ++n)
        gB[n] = B + (size_t)(wc * 128 + n * 16 + l16) * D_DIM + l4 * 8;

    // A read: byte = row*1024 + (((t*4+l4) ^ l16) << 4), row = wr*64+m*16+l16
    int abase[4];
#pragma unroll
    for (int m = 0; m < 4; ++m)
        abase[m] = (wr * 64 + m * 16 + l16) * 1024;

    f32x4 acc[4][8] = {};

    __syncthreads();   // A panel resident (compiler drains vmcnt here, once)

    // ---- barrier-free K-loop: 16 tiles of BK=32 ----
#pragma unroll 4
    for (int t = 0; t < 16; ++t) {
        short8 bf[8];
#pragma unroll
        for (int n = 0; n < 8; ++n)
            bf[n] = *(const short8*)(gB[n] + t * 32);
        short8 af[4];
#pragma unroll
        for (int m = 0; m < 4; ++m)
            af[m] = *(const short8*)((const char*)smA
                    + abase[m] + ((((t * 4 + l4) ^ l16)) << 4));
#pragma unroll
        for (int m = 0; m < 4; ++m)
#pragma unroll
            for (int n = 0; n < 8; ++n)
                acc[m][n] = __builtin_amdgcn_mfma_f32_16x16x32_bf16(
                    af[m], bf[n], acc[m][n], 0, 0, 0);
    }

    // ---- epilogue: numerator + fused row-normalize ----
    // C/D layout: col = l16, row = l4*4 + reg (per 16x16 frag)
    float xs[4][4];
#pragma unroll
    for (int m = 0; m < 4; ++m)
#pragma unroll
        for (int r = 0; r < 4; ++r)
            xs[m][r] = xsq[rbase + wr * 64 + m * 16 + l4 * 4 + r];

    float s[4][4] = {{0.f}};
#pragma unroll
    for (int n = 0; n < 8; ++n) {
        const float cs = csq[wc * 128 + n * 16 + l16];
#pragma unroll
        for (int m = 0; m < 4; ++m)
#pragma unroll
            for (int r = 0; r < 4; ++r) {
                float ns = fmaxf(xs[m][r] - 2.0f * acc[m][n][r] + cs, 0.0f);
                float p = 1.0f / (1.0f + ns);
                acc[m][n][r] = p;
                s[m][r] += p;
            }
    }
    // reduce across the 16 col-lanes of each 16-lane group
#pragma unroll
    for (int m = 0; m < 4; ++m)
#pragma unroll
        for (int r = 0; r < 4; ++r) {
            float v = s[m][r];
            v += __shfl_xor(v, 1, 64);
            v += __shfl_xor(v, 2, 64);
            v += __shfl_xor(v, 4, 64);
            v += __shfl_xor(v, 8, 64);
            s[m][r] = v;
        }

    __syncthreads();   // all waves done reading smA; safe to alias
    float* smRS  = (float*)smA;          // [8 wc][128 rows]
    float* smInv = (float*)smA + 1024;   // [128]
    if (l16 == 0) {
#pragma unroll
        for (int m = 0; m < 4; ++m)
#pragma unroll
            for (int r = 0; r < 4; ++r)
                smRS[wc * 128 + wr * 64 + m * 16 + l4 * 4 + r] = s[m][r];
    }
    __syncthreads();
    if (tid < 128) {
        float t = 0.f;
#pragma unroll
        for (int j = 0; j < 8; ++j) t += smRS[j * 128 + tid];
        smInv[tid] = 1.0f / t;
    }
    __syncthreads();

    float inv[4][4];
#pragma unroll
    for (int m = 0; m < 4; ++m)
#pragma unroll
        for (int r = 0; r < 4; ++r)
            inv[m][r] = smInv[wr * 64 + m * 16 + l4 * 4 + r];   // broadcast

#pragma unroll
    for (int m = 0; m < 4; ++m)
#pragma unroll
        for (int n = 0; n < 8; ++n) {
            const int col = wc * 128 + n * 16 + l16;
#pragma unroll
            for (int r = 0; r < 4; ++r) {
                const int row = rbase + wr * 64 + m * 16 + l4 * 4 + r;
                out[(size_t)row * K_CL + col] = acc[m][n][r] * inv[m][r];
            }
        }
}

extern "C" void kernel_launch(void* const* d_in, const int* in_sizes, int n_in,
                              void* d_out, int out_size, void* d_ws, size_t ws_size,
                              hipStream_t stream) {
    const float* batch   = (const float*)d_in[0];
    const float* centers = (const float*)d_in[1];
    float* out = (float*)d_out;

    char* ws = (char*)d_ws;
    ushort* Abf = (ushort*)ws;                                          // 64 MB
    ushort* Bbf = (ushort*)(ws + (size_t)N_ROWS * D_DIM * 2);          // 1 MB
    float*  xsq = (float*)(ws + (size_t)N_ROWS * D_DIM * 2
                              + (size_t)K_CL * D_DIM * 2);             // 256 KB
    float*  csq = xsq + N_ROWS;                                         // 4 KB
    (void)in_sizes; (void)n_in; (void)out_size; (void)ws_size;

    prep_rows<<<K_CL / 4,   256, 0, stream>>>(centers, Bbf, csq);
    prep_rows<<<N_ROWS / 4, 256, 0, stream>>>(batch, Abf, xsq);
    gemm_fused<<<N_ROWS / BM, 1024, 0, stream>>>(Abf, Bbf, xsq, csq, out);
}

// Round 6
// 240.895 us; speedup vs baseline: 4.1887x; 4.1887x over previous
//
#include <hip/hip_runtime.h>
#include <hip/hip_bf16.h>
#include <stdint.h>

// ClusterAssignment: out[n,k] = q/(row-sum q), q = 1/(1+||x_n-c_k||^2), ALPHA=1
// N=65536, K=1024, D=512, fp32 in/out.
// R6: R5's barrier-free structure with the occupancy bug fixed. R5's 978us was
// pure register spill: __launch_bounds__(1024,2) capped VGPR at 64 (acc alone
// needs 128/lane) -> 2.8GB scratch traffic. Now 512 threads / 8 waves
// (R2-proven ~240-reg fit at 2 waves/SIMD). A panel 64x512 = 64KB staged to
// LDS once (slot^row swizzle), ONE barrier, then 16 K-tiles of
// {8 B global->reg + 4 A ds_read + 32 MFMA} with no barriers/vmcnt pins.
// Fused numerator + row-normalize epilogue (R2-verified) kept.

#define N_ROWS 65536
#define K_CL   1024
#define D_DIM  512
#define BM     64

typedef __attribute__((ext_vector_type(8))) short short8;
typedef __attribute__((ext_vector_type(4))) float f32x4;

__device__ __forceinline__ ushort f2bf(float f) {
    union { float f; uint32_t u; } v; v.f = f;
    uint32_t u = v.u;
    u += 0x7fffu + ((u >> 16) & 1u);   // RNE (inputs are finite normals)
    return (ushort)(u >> 16);
}

__device__ __forceinline__ float waveReduceSum(float s) {
#pragma unroll
    for (int off = 32; off; off >>= 1) s += __shfl_down(s, off, 64);
    return s;
}

// ---- prep: fp32 -> bf16 + row sum-of-squares (one wave per row of 512) ----
__global__ void prep_rows(const float* __restrict__ X, ushort* __restrict__ Xbf,
                          float* __restrict__ sq) {
    const int row  = blockIdx.x * 4 + (threadIdx.x >> 6);
    const int lane = threadIdx.x & 63;
    const float4* src = (const float4*)(X + (size_t)row * D_DIM);
    float4 a = src[lane * 2];
    float4 b = src[lane * 2 + 1];
    float s = (a.x*a.x + a.y*a.y) + (a.z*a.z + a.w*a.w)
            + (b.x*b.x + b.y*b.y) + (b.z*b.z + b.w*b.w);
    uint4 o;
    o.x = (uint32_t)f2bf(a.x) | ((uint32_t)f2bf(a.y) << 16);
    o.y = (uint32_t)f2bf(a.z) | ((uint32_t)f2bf(a.w) << 16);
    o.z = (uint32_t)f2bf(b.x) | ((uint32_t)f2bf(b.y) << 16);
    o.w = (uint32_t)f2bf(b.z) | ((uint32_t)f2bf(b.w) << 16);
    *(uint4*)(Xbf + (size_t)row * D_DIM + lane * 8) = o;
    s = waveReduceSum(s);
    if (lane == 0) sq[row] = s;
}

// ---- fused GEMM + numerator + row-normalize, barrier-free K-loop ----
// Block: 64 rows x full K=1024, 512 threads = 8 waves; wave w owns cluster
// cols [w*128, w*128+128), acc[4][8]. A in LDS (staged once); B global->reg.
__global__ __launch_bounds__(512, 2) void gemm_fused(
    const ushort* __restrict__ A, const ushort* __restrict__ B,
    const float* __restrict__ xsq, const float* __restrict__ csq,
    float* __restrict__ out)
{
    // [row][512] bf16 = 1024 B rows, 64 slots of 16 B; LDS slot s of row r
    // holds global slot s ^ (r & 15).
    __shared__ __align__(16) ushort smA[BM * D_DIM];   // 64 KB

    const int tid  = threadIdx.x;
    const int w    = tid >> 6;                 // 0..7: wave owns cols w*128..+127
    const int lane = tid & 63;
    const int l4 = lane >> 4, l16 = lane & 15;
    const int rbase = blockIdx.x * BM;

    // ---- stage full A panel once: 8 rounds x 8 waves x 1 row (1024 B) ----
#pragma unroll
    for (int i = 0; i < 8; ++i) {
        const int row = i * 8 + w;                  // wave-uniform
        const int sl  = lane ^ (row & 15);          // pre-swizzled source slot
        __builtin_amdgcn_global_load_lds(
            (const __attribute__((address_space(1))) void*)
                (A + (size_t)(rbase + row) * D_DIM + sl * 8),
            (__attribute__((address_space(3))) void*)(smA + (size_t)row * D_DIM),
            16, 0, 0);
    }

    // B per-lane fragment bases: row (w*128 + n*16 + l16), k-slice l4*8
    const ushort* gB[8];
#pragma unroll
    for (int n = 0; n < 8; ++n)
        gB[n] = B + (size_t)(w * 128 + n * 16 + l16) * D_DIM + l4 * 8;

    f32x4 acc[4][8] = {};

    __syncthreads();   // A panel resident (single vmcnt(0) drain, once)

    // ---- barrier-free K-loop: 16 tiles of BK=32 ----
#pragma unroll 2
    for (int t = 0; t < 16; ++t) {
        short8 bf[8];
#pragma unroll
        for (int n = 0; n < 8; ++n)
            bf[n] = *(const short8*)(gB[n] + t * 32);
        short8 af[4];
#pragma unroll
        for (int m = 0; m < 4; ++m) {
            const int row = m * 16 + l16;          // row & 15 == l16
            af[m] = *(const short8*)((const char*)smA
                    + row * 1024 + (((t * 4 + l4) ^ l16) << 4));
        }
#pragma unroll
        for (int m = 0; m < 4; ++m)
#pragma unroll
            for (int n = 0; n < 8; ++n)
                acc[m][n] = __builtin_amdgcn_mfma_f32_16x16x32_bf16(
                    af[m], bf[n], acc[m][n], 0, 0, 0);
    }

    // ---- epilogue: numerator + fused row-normalize (R2-verified) ----
    // C/D layout: col = l16, row = l4*4 + reg (per 16x16 frag)
    float xs[4][4];
#pragma unroll
    for (int m = 0; m < 4; ++m)
#pragma unroll
        for (int r = 0; r < 4; ++r)
            xs[m][r] = xsq[rbase + m * 16 + l4 * 4 + r];

    float s[4][4] = {{0.f}};
#pragma unroll
    for (int n = 0; n < 8; ++n) {
        const float cs = csq[w * 128 + n * 16 + l16];
#pragma unroll
        for (int m = 0; m < 4; ++m)
#pragma unroll
            for (int r = 0; r < 4; ++r) {
                float ns = fmaxf(xs[m][r] - 2.0f * acc[m][n][r] + cs, 0.0f);
                float p = 1.0f / (1.0f + ns);
                acc[m][n][r] = p;
                s[m][r] += p;
            }
    }
    // reduce across the 16 col-lanes of each 16-lane group
#pragma unroll
    for (int m = 0; m < 4; ++m)
#pragma unroll
        for (int r = 0; r < 4; ++r) {
            float v = s[m][r];
            v += __shfl_xor(v, 1, 64);
            v += __shfl_xor(v, 2, 64);
            v += __shfl_xor(v, 4, 64);
            v += __shfl_xor(v, 8, 64);
            s[m][r] = v;
        }

    __syncthreads();   // all waves done reading smA; safe to alias
    float* smRS  = (float*)smA;         // [8 waves][64 rows]
    float* smInv = (float*)smA + 512;   // [64]
    if (l16 == 0) {
#pragma unroll
        for (int m = 0; m < 4; ++m)
#pragma unroll
            for (int r = 0; r < 4; ++r)
                smRS[w * 64 + m * 16 + l4 * 4 + r] = s[m][r];
    }
    __syncthreads();
    if (tid < 64) {
        float t = 0.f;
#pragma unroll
        for (int j = 0; j < 8; ++j) t += smRS[j * 64 + tid];
        smInv[tid] = 1.0f / t;
    }
    __syncthreads();

    float inv[4][4];
#pragma unroll
    for (int m = 0; m < 4; ++m)
#pragma unroll
        for (int r = 0; r < 4; ++r)
            inv[m][r] = smInv[m * 16 + l4 * 4 + r];   // broadcast read

#pragma unroll
    for (int m = 0; m < 4; ++m)
#pragma unroll
        for (int n = 0; n < 8; ++n) {
            const int col = w * 128 + n * 16 + l16;
#pragma unroll
            for (int r = 0; r < 4; ++r) {
                const int row = rbase + m * 16 + l4 * 4 + r;
                out[(size_t)row * K_CL + col] = acc[m][n][r] * inv[m][r];
            }
        }
}

extern "C" void kernel_launch(void* const* d_in, const int* in_sizes, int n_in,
                              void* d_out, int out_size, void* d_ws, size_t ws_size,
                              hipStream_t stream) {
    const float* batch   = (const float*)d_in[0];
    const float* centers = (const float*)d_in[1];
    float* out = (float*)d_out;

    char* ws = (char*)d_ws;
    ushort* Abf = (ushort*)ws;                                          // 64 MB
    ushort* Bbf = (ushort*)(ws + (size_t)N_ROWS * D_DIM * 2);          // 1 MB
    float*  xsq = (float*)(ws + (size_t)N_ROWS * D_DIM * 2
                              + (size_t)K_CL * D_DIM * 2);             // 256 KB
    float*  csq = xsq + N_ROWS;                                         // 4 KB
    (void)in_sizes; (void)n_in; (void)out_size; (void)ws_size;

    prep_rows<<<K_CL / 4,   256, 0, stream>>>(centers, Bbf, csq);
    prep_rows<<<N_ROWS / 4, 256, 0, stream>>>(batch, Abf, xsq);
    gemm_fused<<<N_ROWS / BM, 512, 0, stream>>>(Abf, Bbf, xsq, csq, out);
}

// Round 7
// 231.556 us; speedup vs baseline: 4.3577x; 1.0403x over previous
//
#include <hip/hip_runtime.h>
#include <hip/hip_bf16.h>
#include <stdint.h>

// ClusterAssignment: out[n,k] = q/(row-sum q), q = 1/(1+||x_n-c_k||^2), ALPHA=1
// N=65536, K=1024, D=512, fp32 in/out.
// R7: persistent full-K pipeline. R2-R6 all hit a ~160-210us wall: depth-1
// prefetch forced a full L2-transfer wait per tile boundary, and per-block
// epilogues serialized at 1 block/CU. Now: 256 persistent blocks x 4 panels;
// wave w stages ITS OWN B rows (gload_lds) so a uniform counted vmcnt(9)
// paces the pipe (in-order retirement also drains epilogue stores exactly
// once per panel, at L2-ack speed); A (4KB/tile) staged redundantly by both
// wave-halves for uniform issue counts. Raw s_barrier pairs (no vmcnt(0)
// drains in steady state). Swizzle + fused normalize epilogue R4-verified.

#define N_ROWS 65536
#define K_CL   1024
#define D_DIM  512

typedef __attribute__((ext_vector_type(8))) short short8;
typedef __attribute__((ext_vector_type(4))) float f32x4;

#define SCHED0() __builtin_amdgcn_sched_barrier(0)

__device__ __forceinline__ ushort f2bf(float f) {
    union { float f; uint32_t u; } v; v.f = f;
    uint32_t u = v.u;
    u += 0x7fffu + ((u >> 16) & 1u);   // RNE (inputs are finite normals)
    return (ushort)(u >> 16);
}

__device__ __forceinline__ float waveReduceSum(float s) {
#pragma unroll
    for (int off = 32; off; off >>= 1) s += __shfl_down(s, off, 64);
    return s;
}

// ---- prep: fp32 -> bf16 + row sum-of-squares (one wave per row of 512) ----
__global__ void prep_rows(const float* __restrict__ X, ushort* __restrict__ Xbf,
                          float* __restrict__ sq) {
    const int row  = blockIdx.x * 4 + (threadIdx.x >> 6);
    const int lane = threadIdx.x & 63;
    const float4* src = (const float4*)(X + (size_t)row * D_DIM);
    float4 a = src[lane * 2];
    float4 b = src[lane * 2 + 1];
    float s = (a.x*a.x + a.y*a.y) + (a.z*a.z + a.w*a.w)
            + (b.x*b.x + b.y*b.y) + (b.z*b.z + b.w*b.w);
    uint4 o;
    o.x = (uint32_t)f2bf(a.x) | ((uint32_t)f2bf(a.y) << 16);
    o.y = (uint32_t)f2bf(a.z) | ((uint32_t)f2bf(a.w) << 16);
    o.z = (uint32_t)f2bf(b.x) | ((uint32_t)f2bf(b.y) << 16);
    o.w = (uint32_t)f2bf(b.z) | ((uint32_t)f2bf(b.w) << 16);
    *(uint4*)(Xbf + (size_t)row * D_DIM + lane * 8) = o;
    s = waveReduceSum(s);
    if (lane == 0) sq[row] = s;
}

// ---- persistent fused GEMM + numerator + row-normalize ----
// 256 blocks x 512 threads (8 waves). Block handles panels bid+256*i (i<4),
// panel = 64 rows x full K=1024; wave w owns cluster cols [w*128, w*128+128).
// 64 global groups of BK=32; group G: panel G>>4, k0=(G&15)*32.
__global__ __launch_bounds__(512, 2) void gemm_fused(
    const ushort* __restrict__ A, const ushort* __restrict__ B,
    const float* __restrict__ xsq, const float* __restrict__ csq,
    float* __restrict__ out)
{
    // 64B rows (32 bf16, 4 slots of 16B); LDS slot s of row r holds global
    // slot s ^ ((r>>1)&3)  [R4-verified, 0 bank conflicts].
    __shared__ __align__(16) ushort smA[2][2048];       // 2 x 4 KB
    __shared__ __align__(16) ushort smB[8][2][4096];    // 8 waves x 2 x 8 KB
    __shared__ float smR[576];                          // row-sum scratch

    const int tid  = threadIdx.x;
    const int w    = tid >> 6;
    const int lane = tid & 63;
    const int l4 = lane >> 4, l16 = lane & 15;
    const int bid = blockIdx.x;

    // staging constants (per-lane, pre-swizzled source; linear LDS dest)
    const uint arow  = (uint)((tid & 255) >> 2);                       // 0..63
    const uint aslot = (uint)((tid & 3) ^ ((tid >> 3) & 3)) * 8u;      // elems
    const uint boffc = (uint)(w * 128 + (lane >> 2)) * 512u
                     + (uint)((lane & 3) ^ ((lane >> 3) & 3)) * 8u;

    // read-side byte offsets (within smA[sl] / smB[w][sl])
    const int swz = ((l16 >> 1) & 3) << 4;
    int aoff[4], boff[8];
#pragma unroll
    for (int m = 0; m < 4; ++m) aoff[m] = (m*16 + l16)*64 + ((l4*16) ^ swz);
#pragma unroll
    for (int n = 0; n < 8; ++n) boff[n] = (n*16 + l16)*64 + ((l4*16) ^ swz);

    f32x4 acc[4][8] = {};

#define STAGE_GRP(H) do {                                                    \
        const int  _sl = (H) & 1;                                            \
        const uint _k0 = (uint)(((H) & 15) * 32);                            \
        const uint _pr = (uint)(bid + 256 * ((H) >> 4)) * 64u;               \
        __builtin_amdgcn_global_load_lds(                                    \
            (const __attribute__((address_space(1))) void*)                  \
                (A + (size_t)(_pr + arow) * 512u + _k0 + aslot),             \
            (__attribute__((address_space(3))) void*)(&smA[_sl][(w & 3) * 512]), \
            16, 0, 0);                                                       \
        _Pragma("unroll")                                                    \
        for (int _i = 0; _i < 8; ++_i)                                       \
            __builtin_amdgcn_global_load_lds(                                \
                (const __attribute__((address_space(1))) void*)              \
                    (B + (size_t)boffc + (size_t)_i * 8192u + _k0),          \
                (__attribute__((address_space(3))) void*)(&smB[w][_sl][_i * 512]), \
                16, 0, 0);                                                   \
    } while (0)

#define LBAR() do { asm volatile("s_waitcnt lgkmcnt(0)" ::: "memory");       \
        SCHED0(); __builtin_amdgcn_s_barrier(); SCHED0(); } while (0)

    STAGE_GRP(0);   // prologue

    for (int G = 0; G < 64; ++G) {
        SCHED0(); __builtin_amdgcn_s_barrier(); SCHED0();      // bar1: bufs free
        if (G < 63) {
            STAGE_GRP(G + 1);
            // own stage(G) ops (1 group old) + anything older (incl. epilogue
            // stores) drain; the 9 just-issued stage(G+1) ops stay in flight.
            asm volatile("s_waitcnt vmcnt(9)" ::: "memory");
        } else {
            asm volatile("s_waitcnt vmcnt(0)" ::: "memory");
        }
        SCHED0(); __builtin_amdgcn_s_barrier(); SCHED0();      // bar2: data ready

        const int sl = G & 1;
        const char* bA = (const char*)&smA[sl][0];
        const char* bB = (const char*)&smB[w][sl][0];
        short8 af[4], bf[8];
#pragma unroll
        for (int m = 0; m < 4; ++m) af[m] = *(const short8*)(bA + aoff[m]);
#pragma unroll
        for (int n = 0; n < 8; ++n) bf[n] = *(const short8*)(bB + boff[n]);

        __builtin_amdgcn_s_setprio(1);
#pragma unroll
        for (int m = 0; m < 4; ++m)
#pragma unroll
            for (int n = 0; n < 8; ++n)
                acc[m][n] = __builtin_amdgcn_mfma_f32_16x16x32_bf16(
                    af[m], bf[n], acc[m][n], 0, 0, 0);
        __builtin_amdgcn_s_setprio(0);

        if ((G & 15) == 15) {
            // ---- panel epilogue: numerator + fused row-normalize ----
            const size_t prow0 = (size_t)(bid + 256 * (G >> 4)) * 64u;
            float xs[4][4];
#pragma unroll
            for (int m = 0; m < 4; ++m)
#pragma unroll
                for (int r = 0; r < 4; ++r)
                    xs[m][r] = xsq[prow0 + m*16 + l4*4 + r];

            float s[4][4] = {{0.f}};
#pragma unroll
            for (int n = 0; n < 8; ++n) {
                const float cs = csq[w*128 + n*16 + l16];
#pragma unroll
                for (int m = 0; m < 4; ++m)
#pragma unroll
                    for (int r = 0; r < 4; ++r) {
                        float ns = fmaxf(xs[m][r] - 2.0f*acc[m][n][r] + cs, 0.0f);
                        float p = 1.0f / (1.0f + ns);
                        acc[m][n][r] = p;
                        s[m][r] += p;
                    }
            }
#pragma unroll
            for (int m = 0; m < 4; ++m)
#pragma unroll
                for (int r = 0; r < 4; ++r) {
                    float v = s[m][r];
                    v += __shfl_xor(v, 1, 64);
                    v += __shfl_xor(v, 2, 64);
                    v += __shfl_xor(v, 4, 64);
                    v += __shfl_xor(v, 8, 64);
                    s[m][r] = v;
                }
            if (l16 == 0) {
#pragma unroll
                for (int m = 0; m < 4; ++m)
#pragma unroll
                    for (int r = 0; r < 4; ++r)
                        smR[w*64 + m*16 + l4*4 + r] = s[m][r];
            }
            LBAR();
            if (tid < 64) {
                float t = 0.f;
#pragma unroll
                for (int j = 0; j < 8; ++j) t += smR[j*64 + tid];
                smR[512 + tid] = 1.0f / t;
            }
            LBAR();
            float inv[4][4];
#pragma unroll
            for (int m = 0; m < 4; ++m)
#pragma unroll
                for (int r = 0; r < 4; ++r)
                    inv[m][r] = smR[512 + m*16 + l4*4 + r];
#pragma unroll
            for (int m = 0; m < 4; ++m)
#pragma unroll
                for (int n = 0; n < 8; ++n) {
                    const int col = w*128 + n*16 + l16;
#pragma unroll
                    for (int r = 0; r < 4; ++r)
                        out[(prow0 + m*16 + l4*4 + r) * K_CL + col]
                            = acc[m][n][r] * inv[m][r];
                }
#pragma unroll
            for (int m = 0; m < 4; ++m)
#pragma unroll
                for (int n = 0; n < 8; ++n)
                    acc[m][n] = (f32x4){0.f, 0.f, 0.f, 0.f};
        }
    }
#undef STAGE_GRP
#undef LBAR
}

extern "C" void kernel_launch(void* const* d_in, const int* in_sizes, int n_in,
                              void* d_out, int out_size, void* d_ws, size_t ws_size,
                              hipStream_t stream) {
    const float* batch   = (const float*)d_in[0];
    const float* centers = (const float*)d_in[1];
    float* out = (float*)d_out;

    char* ws = (char*)d_ws;
    ushort* Abf = (ushort*)ws;                                          // 64 MB
    ushort* Bbf = (ushort*)(ws + (size_t)N_ROWS * D_DIM * 2);          // 1 MB
    float*  xsq = (float*)(ws + (size_t)N_ROWS * D_DIM * 2
                              + (size_t)K_CL * D_DIM * 2);             // 256 KB
    float*  csq = xsq + N_ROWS;                                         // 4 KB
    (void)in_sizes; (void)n_in; (void)out_size; (void)ws_size;

    prep_rows<<<K_CL / 4,   256, 0, stream>>>(centers, Bbf, csq);
    prep_rows<<<N_ROWS / 4, 256, 0, stream>>>(batch, Abf, xsq);
    gemm_fused<<<256, 512, 0, stream>>>(Abf, Bbf, xsq, csq, out);
}

// Round 8
// 228.094 us; speedup vs baseline: 4.4238x; 1.0152x over previous
//
#include <hip/hip_runtime.h>
#include <hip/hip_bf16.h>
#include <stdint.h>

// ClusterAssignment: out[n,k] = q/(row-sum q), q = 1/(1+||x_n-c_k||^2), ALPHA=1
// N=65536, K=1024, D=512, fp32 in/out.
// R8 = R7 + cache policy ONLY. Diagnosis: R2-R7 (5 schedules) all ~160-210us
// with effective staging delivery ~10 B/cyc/CU = the HBM/fabric number, not
// L2's ~56. The 256MB output-write stream + A stream thrash per-XCD L2, so
// B (1MB) re-reads (1GB total) come from L3/fabric -> ~7TB/s fabric ceiling.
// Fix: NT (non-temporal) output stores + NT A staging loads (aux=2) so B
// stays L2-resident. Everything else byte-identical to R7 (passed, absmax
// 7.6e-6).

#define N_ROWS 65536
#define K_CL   1024
#define D_DIM  512

typedef __attribute__((ext_vector_type(8))) short short8;
typedef __attribute__((ext_vector_type(4))) float f32x4;

#define SCHED0() __builtin_amdgcn_sched_barrier(0)

__device__ __forceinline__ ushort f2bf(float f) {
    union { float f; uint32_t u; } v; v.f = f;
    uint32_t u = v.u;
    u += 0x7fffu + ((u >> 16) & 1u);   // RNE (inputs are finite normals)
    return (ushort)(u >> 16);
}

__device__ __forceinline__ float waveReduceSum(float s) {
#pragma unroll
    for (int off = 32; off; off >>= 1) s += __shfl_down(s, off, 64);
    return s;
}

// ---- prep: fp32 -> bf16 + row sum-of-squares (one wave per row of 512) ----
__global__ void prep_rows(const float* __restrict__ X, ushort* __restrict__ Xbf,
                          float* __restrict__ sq) {
    const int row  = blockIdx.x * 4 + (threadIdx.x >> 6);
    const int lane = threadIdx.x & 63;
    const float4* src = (const float4*)(X + (size_t)row * D_DIM);
    float4 a = src[lane * 2];
    float4 b = src[lane * 2 + 1];
    float s = (a.x*a.x + a.y*a.y) + (a.z*a.z + a.w*a.w)
            + (b.x*b.x + b.y*b.y) + (b.z*b.z + b.w*b.w);
    uint4 o;
    o.x = (uint32_t)f2bf(a.x) | ((uint32_t)f2bf(a.y) << 16);
    o.y = (uint32_t)f2bf(a.z) | ((uint32_t)f2bf(a.w) << 16);
    o.z = (uint32_t)f2bf(b.x) | ((uint32_t)f2bf(b.y) << 16);
    o.w = (uint32_t)f2bf(b.z) | ((uint32_t)f2bf(b.w) << 16);
    *(uint4*)(Xbf + (size_t)row * D_DIM + lane * 8) = o;
    s = waveReduceSum(s);
    if (lane == 0) sq[row] = s;
}

// ---- persistent fused GEMM + numerator + row-normalize ----
// 256 blocks x 512 threads (8 waves). Block handles panels bid+256*i (i<4),
// panel = 64 rows x full K=1024; wave w owns cluster cols [w*128, w*128+128).
// 64 global groups of BK=32; group G: panel G>>4, k0=(G&15)*32.
__global__ __launch_bounds__(512, 2) void gemm_fused(
    const ushort* __restrict__ A, const ushort* __restrict__ B,
    const float* __restrict__ xsq, const float* __restrict__ csq,
    float* __restrict__ out)
{
    // 64B rows (32 bf16, 4 slots of 16B); LDS slot s of row r holds global
    // slot s ^ ((r>>1)&3)  [R4-verified, 0 bank conflicts].
    __shared__ __align__(16) ushort smA[2][2048];       // 2 x 4 KB
    __shared__ __align__(16) ushort smB[8][2][4096];    // 8 waves x 2 x 8 KB
    __shared__ float smR[576];                          // row-sum scratch

    const int tid  = threadIdx.x;
    const int w    = tid >> 6;
    const int lane = tid & 63;
    const int l4 = lane >> 4, l16 = lane & 15;
    const int bid = blockIdx.x;

    // staging constants (per-lane, pre-swizzled source; linear LDS dest)
    const uint arow  = (uint)((tid & 255) >> 2);                       // 0..63
    const uint aslot = (uint)((tid & 3) ^ ((tid >> 3) & 3)) * 8u;      // elems
    const uint boffc = (uint)(w * 128 + (lane >> 2)) * 512u
                     + (uint)((lane & 3) ^ ((lane >> 3) & 3)) * 8u;

    // read-side byte offsets (within smA[sl] / smB[w][sl])
    const int swz = ((l16 >> 1) & 3) << 4;
    int aoff[4], boff[8];
#pragma unroll
    for (int m = 0; m < 4; ++m) aoff[m] = (m*16 + l16)*64 + ((l4*16) ^ swz);
#pragma unroll
    for (int n = 0; n < 8; ++n) boff[n] = (n*16 + l16)*64 + ((l4*16) ^ swz);

    f32x4 acc[4][8] = {};

    // A staged NT (aux=2: nt bit) -- streamed once, must not evict B from L2.
    // B staged default policy -- the only L2-resident reuse stream.
#define STAGE_GRP(H) do {                                                    \
        const int  _sl = (H) & 1;                                            \
        const uint _k0 = (uint)(((H) & 15) * 32);                            \
        const uint _pr = (uint)(bid + 256 * ((H) >> 4)) * 64u;               \
        __builtin_amdgcn_global_load_lds(                                    \
            (const __attribute__((address_space(1))) void*)                  \
                (A + (size_t)(_pr + arow) * 512u + _k0 + aslot),             \
            (__attribute__((address_space(3))) void*)(&smA[_sl][(w & 3) * 512]), \
            16, 0, 2);                                                       \
        _Pragma("unroll")                                                    \
        for (int _i = 0; _i < 8; ++_i)                                       \
            __builtin_amdgcn_global_load_lds(                                \
                (const __attribute__((address_space(1))) void*)              \
                    (B + (size_t)boffc + (size_t)_i * 8192u + _k0),          \
                (__attribute__((address_space(3))) void*)(&smB[w][_sl][_i * 512]), \
                16, 0, 0);                                                   \
    } while (0)

#define LBAR() do { asm volatile("s_waitcnt lgkmcnt(0)" ::: "memory");       \
        SCHED0(); __builtin_amdgcn_s_barrier(); SCHED0(); } while (0)

    STAGE_GRP(0);   // prologue

    for (int G = 0; G < 64; ++G) {
        SCHED0(); __builtin_amdgcn_s_barrier(); SCHED0();      // bar1: bufs free
        if (G < 63) {
            STAGE_GRP(G + 1);
            // own stage(G) ops (1 group old) + anything older (incl. epilogue
            // stores) drain; the 9 just-issued stage(G+1) ops stay in flight.
            asm volatile("s_waitcnt vmcnt(9)" ::: "memory");
        } else {
            asm volatile("s_waitcnt vmcnt(0)" ::: "memory");
        }
        SCHED0(); __builtin_amdgcn_s_barrier(); SCHED0();      // bar2: data ready

        const int sl = G & 1;
        const char* bA = (const char*)&smA[sl][0];
        const char* bB = (const char*)&smB[w][sl][0];
        short8 af[4], bf[8];
#pragma unroll
        for (int m = 0; m < 4; ++m) af[m] = *(const short8*)(bA + aoff[m]);
#pragma unroll
        for (int n = 0; n < 8; ++n) bf[n] = *(const short8*)(bB + boff[n]);

        __builtin_amdgcn_s_setprio(1);
#pragma unroll
        for (int m = 0; m < 4; ++m)
#pragma unroll
            for (int n = 0; n < 8; ++n)
                acc[m][n] = __builtin_amdgcn_mfma_f32_16x16x32_bf16(
                    af[m], bf[n], acc[m][n], 0, 0, 0);
        __builtin_amdgcn_s_setprio(0);

        if ((G & 15) == 15) {
            // ---- panel epilogue: numerator + fused row-normalize ----
            const size_t prow0 = (size_t)(bid + 256 * (G >> 4)) * 64u;
            float xs[4][4];
#pragma unroll
            for (int m = 0; m < 4; ++m)
#pragma unroll
                for (int r = 0; r < 4; ++r)
                    xs[m][r] = xsq[prow0 + m*16 + l4*4 + r];

            float s[4][4] = {{0.f}};
#pragma unroll
            for (int n = 0; n < 8; ++n) {
                const float cs = csq[w*128 + n*16 + l16];
#pragma unroll
                for (int m = 0; m < 4; ++m)
#pragma unroll
                    for (int r = 0; r < 4; ++r) {
                        float ns = fmaxf(xs[m][r] - 2.0f*acc[m][n][r] + cs, 0.0f);
                        float p = 1.0f / (1.0f + ns);
                        acc[m][n][r] = p;
                        s[m][r] += p;
                    }
            }
#pragma unroll
            for (int m = 0; m < 4; ++m)
#pragma unroll
                for (int r = 0; r < 4; ++r) {
                    float v = s[m][r];
                    v += __shfl_xor(v, 1, 64);
                    v += __shfl_xor(v, 2, 64);
                    v += __shfl_xor(v, 4, 64);
                    v += __shfl_xor(v, 8, 64);
                    s[m][r] = v;
                }
            if (l16 == 0) {
#pragma unroll
                for (int m = 0; m < 4; ++m)
#pragma unroll
                    for (int r = 0; r < 4; ++r)
                        smR[w*64 + m*16 + l4*4 + r] = s[m][r];
            }
            LBAR();
            if (tid < 64) {
                float t = 0.f;
#pragma unroll
                for (int j = 0; j < 8; ++j) t += smR[j*64 + tid];
                smR[512 + tid] = 1.0f / t;
            }
            LBAR();
            float inv[4][4];
#pragma unroll
            for (int m = 0; m < 4; ++m)
#pragma unroll
                for (int r = 0; r < 4; ++r)
                    inv[m][r] = smR[512 + m*16 + l4*4 + r];
#pragma unroll
            for (int m = 0; m < 4; ++m)
#pragma unroll
                for (int n = 0; n < 8; ++n) {
                    const int col = w*128 + n*16 + l16;
#pragma unroll
                    for (int r = 0; r < 4; ++r)
                        __builtin_nontemporal_store(
                            acc[m][n][r] * inv[m][r],
                            &out[(prow0 + m*16 + l4*4 + r) * K_CL + col]);
                }
#pragma unroll
            for (int m = 0; m < 4; ++m)
#pragma unroll
                for (int n = 0; n < 8; ++n)
                    acc[m][n] = (f32x4){0.f, 0.f, 0.f, 0.f};
        }
    }
#undef STAGE_GRP
#undef LBAR
}

extern "C" void kernel_launch(void* const* d_in, const int* in_sizes, int n_in,
                              void* d_out, int out_size, void* d_ws, size_t ws_size,
                              hipStream_t stream) {
    const float* batch   = (const float*)d_in[0];
    const float* centers = (const float*)d_in[1];
    float* out = (float*)d_out;

    char* ws = (char*)d_ws;
    ushort* Abf = (ushort*)ws;                                          // 64 MB
    ushort* Bbf = (ushort*)(ws + (size_t)N_ROWS * D_DIM * 2);          // 1 MB
    float*  xsq = (float*)(ws + (size_t)N_ROWS * D_DIM * 2
                              + (size_t)K_CL * D_DIM * 2);             // 256 KB
    float*  csq = xsq + N_ROWS;                                         // 4 KB
    (void)in_sizes; (void)n_in; (void)out_size; (void)ws_size;

    prep_rows<<<K_CL / 4,   256, 0, stream>>>(centers, Bbf, csq);
    prep_rows<<<N_ROWS / 4, 256, 0, stream>>>(batch, Abf, xsq);
    gemm_fused<<<256, 512, 0, stream>>>(Abf, Bbf, xsq, csq, out);
}